// Round 12
// baseline (50.076 us; speedup 1.0000x reference)
//
#include <hip/hip_runtime.h>

#define HW 9216
#define W 96
#define H 96
#define NC 256
#define NT 49
#define NPAIR 25
#define EPSV 1e-5f

#define TSX 16
#define TSY 24          // tile rows; each thread owns 2 adjacent rows
#define NTHR 192        // 16 x 12
#define HROWS 30        // 24 + 6
#define HCOLS 22
#define CC 8
#define NZ 32

#define OUTS 384
#define SRCP 10

typedef _Float16 half8 __attribute__((ext_vector_type(8)));
typedef _Float16 half2v __attribute__((ext_vector_type(2)));

// ---- step1: fused pack + 2-pass normalize + 2-px message passing -----------
__global__ __launch_bounds__(NTHR) void step1_kernel(const float* __restrict__ x,
                                                     const float* __restrict__ w,
                                                     _Float16* __restrict__ x1h,
                                                     half2v* __restrict__ nwh) {
    __shared__ half8 xs[HROWS][HCOLS];  // 10560 B
    const int tx = threadIdx.x & 15;
    const int tyl = threadIdx.x >> 4;   // 0..11
    const int bx = blockIdx.x * TSX;
    const int by = blockIdx.y * TSY;
    const int px = bx + tx;
    const int py0 = by + 2 * tyl;
    const int p0 = py0 * W + px;
    const int p1 = p0 + W;
    const int z = blockIdx.z;

    // ---- stage 8 channels' 30x22 halo, packed fp16 (zero-padded) ----
    const float* __restrict__ xb = x + (size_t)z * CC * HW;
#pragma unroll
    for (int it = 0; it < 4; ++it) {
        const int i = threadIdx.x + it * NTHR;
        if (i < HROWS * HCOLS) {
            const int hy = i / HCOLS;
            const int hx = i - hy * HCOLS;
            const int gy = by - 3 + hy;
            const int gx = bx - 3 + hx;
            half8 h;
#pragma unroll
            for (int c = 0; c < 8; ++c) h[c] = (_Float16)0.f;
            if ((unsigned)gy < (unsigned)H && (unsigned)gx < (unsigned)W) {
                const float* sp = xb + gy * W + gx;
#pragma unroll
                for (int c = 0; c < 8; ++c) h[c] = (_Float16)sp[c * HW];
            }
            xs[hy][hx] = h;
        }
    }

    // ---- weights for both pixels: 2-pass normalize -> packed half2 ----
    half2v wu0[NPAIR], wu1[NPAIR];
    {
        float s0 = 0.f, s1 = 0.f;
#pragma unroll
        for (int t = 0; t < NT; ++t) { s0 += w[t * HW + p0]; s1 += w[t * HW + p1]; }
        const float inv0 = 1.f / (s0 + EPSV);
        const float inv1 = 1.f / (s1 + EPSV);
#pragma unroll
        for (int i = 0; i < NPAIR; ++i) {
            const int t0 = 2 * i, t1 = 2 * i + 1;
            half2v h0, h1;
            h0[0] = (_Float16)(w[t0 * HW + p0] * inv0);
            h0[1] = (t1 < NT) ? (_Float16)(w[t1 * HW + p0] * inv0) : (_Float16)0.f;
            h1[0] = (_Float16)(w[t0 * HW + p1] * inv1);
            h1[1] = (t1 < NT) ? (_Float16)(w[t1 * HW + p1] * inv1) : (_Float16)0.f;
            wu0[i] = h0;
            wu1[i] = h1;
        }
    }

    // z==0 blocks publish packed weights for step2
    if (z == 0) {
#pragma unroll
        for (int i = 0; i < NPAIR; ++i) {
            nwh[i * HW + p0] = wu0[i];
            nwh[i * HW + p1] = wu1[i];
        }
    }
    __syncthreads();

    // ---- taps: 8 shared rows, 56 ds_read_b128 feed both pixels ----
    float acc0[8], acc1[8];
#pragma unroll
    for (int k = 0; k < 8; ++k) { acc0[k] = 0.f; acc1[k] = 0.f; }

#pragma unroll
    for (int r = 0; r < 8; ++r) {
        const int row = 2 * tyl + r;
#pragma unroll
        for (int j = 0; j < 7; ++j) {
            const half8 v = xs[row][tx + j];
            if (r < 7) {
                const int t = r * 7 + j;
                const float wf = (float)wu0[t >> 1][t & 1];
#pragma unroll
                for (int k = 0; k < 8; ++k)
                    acc0[k] = fmaf(wf, (float)v[k], acc0[k]);
            }
            if (r >= 1) {
                const int t = (r - 1) * 7 + j;
                const float wf = (float)wu1[t >> 1][t & 1];
#pragma unroll
                for (int k = 0; k < 8; ++k)
                    acc1[k] = fmaf(wf, (float)v[k], acc1[k]);
            }
        }
    }

    half8 h0, h1;
#pragma unroll
    for (int k = 0; k < 8; ++k) { h0[k] = (_Float16)acc0[k]; h1[k] = (_Float16)acc1[k]; }
    *(half8*)(x1h + ((size_t)z * HW + p0) * 8) = h0;
    *(half8*)(x1h + ((size_t)z * HW + p1) * 8) = h1;
}

// ---- step2: lean 2-px + partial 1x1 conv -----------------------------------
__global__ __launch_bounds__(NTHR) void step2_kernel(const _Float16* __restrict__ xin,
                                                     const half2v* __restrict__ nwh,
                                                     const float* __restrict__ cw,
                                                     float* __restrict__ partial) {
    __shared__ half8 xs[HROWS][HCOLS];
    const int tx = threadIdx.x & 15;
    const int tyl = threadIdx.x >> 4;
    const int bx = blockIdx.x * TSX;
    const int by = blockIdx.y * TSY;
    const int px = bx + tx;
    const int py0 = by + 2 * tyl;
    const int p0 = py0 * W + px;
    const int p1 = p0 + W;
    const int z = blockIdx.z;

    const _Float16* __restrict__ xz = xin + (size_t)z * HW * 8;
#pragma unroll
    for (int it = 0; it < 4; ++it) {
        const int i = threadIdx.x + it * NTHR;
        if (i < HROWS * HCOLS) {
            const int hy = i / HCOLS;
            const int hx = i - hy * HCOLS;
            const int gy = by - 3 + hy;
            const int gx = bx - 3 + hx;
            half8 v;
#pragma unroll
            for (int c = 0; c < 8; ++c) v[c] = (_Float16)0.f;
            if ((unsigned)gy < (unsigned)H && (unsigned)gx < (unsigned)W)
                v = *(const half8*)(xz + (size_t)(gy * W + gx) * 8);
            xs[hy][hx] = v;
        }
    }

    half2v wu0[NPAIR], wu1[NPAIR];
#pragma unroll
    for (int i = 0; i < NPAIR; ++i) {
        wu0[i] = nwh[i * HW + p0];
        wu1[i] = nwh[i * HW + p1];
    }
    __syncthreads();

    float acc0[8], acc1[8];
#pragma unroll
    for (int k = 0; k < 8; ++k) { acc0[k] = 0.f; acc1[k] = 0.f; }

#pragma unroll
    for (int r = 0; r < 8; ++r) {
        const int row = 2 * tyl + r;
#pragma unroll
        for (int j = 0; j < 7; ++j) {
            const half8 v = xs[row][tx + j];
            if (r < 7) {
                const int t = r * 7 + j;
                const float wf = (float)wu0[t >> 1][t & 1];
#pragma unroll
                for (int k = 0; k < 8; ++k)
                    acc0[k] = fmaf(wf, (float)v[k], acc0[k]);
            }
            if (r >= 1) {
                const int t = (r - 1) * 7 + j;
                const float wf = (float)wu1[t >> 1][t & 1];
#pragma unroll
                for (int k = 0; k < 8; ++k)
                    acc1[k] = fmaf(wf, (float)v[k], acc1[k]);
            }
        }
    }

    const int cbase = z * CC;
    float o00 = 0.f, o01 = 0.f, o02 = 0.f;
    float o10 = 0.f, o11 = 0.f, o12 = 0.f;
#pragma unroll
    for (int k = 0; k < 8; ++k) {
        const int c = cbase + k;
        const float cw0 = cw[c], cw1 = cw[NC + c], cw2 = cw[2 * NC + c];
        o00 = fmaf(acc0[k], cw0, o00);
        o01 = fmaf(acc0[k], cw1, o01);
        o02 = fmaf(acc0[k], cw2, o02);
        o10 = fmaf(acc1[k], cw0, o10);
        o11 = fmaf(acc1[k], cw1, o11);
        o12 = fmaf(acc1[k], cw2, o12);
    }
    partial[(z * 3 + 0) * HW + p0] = o00;
    partial[(z * 3 + 1) * HW + p0] = o01;
    partial[(z * 3 + 2) * HW + p0] = o02;
    partial[(z * 3 + 0) * HW + p1] = o10;
    partial[(z * 3 + 1) * HW + p1] = o11;
    partial[(z * 3 + 2) * HW + p1] = o12;
}

// ---- fused z-reduce + bias + bilinear x4 upsample --------------------------
__global__ __launch_bounds__(256) void upsample_kernel(const float* __restrict__ partial,
                                                       const float* __restrict__ cb,
                                                       float* __restrict__ dst) {
    __shared__ float cvs[3][SRCP][SRCP];
    const int X = blockIdx.x * 32;
    const int Y = blockIdx.y * 32;
    const int x0s = X >> 2;
    const int y0s = Y >> 2;

    for (int e = threadIdx.x; e < 3 * SRCP * SRCP; e += 256) {
        int ch = e / (SRCP * SRCP);
        int r = e - ch * (SRCP * SRCP);
        int sy = r / SRCP;
        int sx = r - sy * SRCP;
        int gy = min(max(y0s - 1 + sy, 0), H - 1);
        int gx = min(max(x0s - 1 + sx, 0), W - 1);
        const int pp = gy * W + gx;
        float sum = cb[ch];
#pragma unroll
        for (int z = 0; z < NZ; ++z) sum += partial[(z * 3 + ch) * HW + pp];
        cvs[ch][sy][sx] = sum;
    }
    __syncthreads();

    const int xl = threadIdx.x & 31;
    const int yl0 = threadIdx.x >> 5;
    const int xo = X + xl;
    const float sxf = xo * 0.25f - 0.375f;
    const float fxf = floorf(sxf);
    const int jx = (int)fxf - (x0s - 1);
    const float fx = sxf - fxf;

#pragma unroll
    for (int k = 0; k < 4; ++k) {
        const int yo = Y + yl0 + 8 * k;
        const float syf = yo * 0.25f - 0.375f;
        const float fyf = floorf(syf);
        const int jy = (int)fyf - (y0s - 1);
        const float fy = syf - fyf;
#pragma unroll
        for (int ch = 0; ch < 3; ++ch) {
            const float v00 = cvs[ch][jy][jx], v01 = cvs[ch][jy][jx + 1];
            const float v10 = cvs[ch][jy + 1][jx], v11 = cvs[ch][jy + 1][jx + 1];
            const float v0 = v00 + (v01 - v00) * fx;
            const float v1 = v10 + (v11 - v10) * fx;
            dst[ch * OUTS * OUTS + yo * OUTS + xo] = v0 + (v1 - v0) * fy;
        }
    }
}

extern "C" void kernel_launch(void* const* d_in, const int* in_sizes, int n_in,
                              void* d_out, int out_size, void* d_ws, size_t ws_size,
                              hipStream_t stream) {
    const float* input  = (const float*)d_in[0];   // (1,256,96,96)
    const float* weight = (const float*)d_in[1];   // (1,49,9216)
    const float* conv_w = (const float*)d_in[2];   // (3,256)
    const float* conv_b = (const float*)d_in[3];   // (3,)
    float* out = (float*)d_out;                    // (1,3,384,384)

    char* ws = (char*)d_ws;
    _Float16* x1h   = (_Float16*)ws;                           // 4.72 MB
    half2v*   nwh   = (half2v*)(ws + (size_t)NZ * HW * 8 * 2); // 0.92 MB
    float*  partial = (float*)((char*)nwh + (size_t)NPAIR * HW * 4);

    dim3 g(W / TSX, H / TSY, NZ);             // (6,4,32) = 768 blocks, 3/CU exact
    step1_kernel<<<g, NTHR, 0, stream>>>(input, weight, x1h, nwh);
    step2_kernel<<<g, NTHR, 0, stream>>>(x1h, nwh, conv_w, partial);

    dim3 gu(OUTS / 32, OUTS / 32);            // (12,12)
    upsample_kernel<<<gu, 256, 0, stream>>>(partial, conv_b, out);
}

// Round 13
// 44.760 us; speedup vs baseline: 1.1188x; 1.1188x over previous
//
#include <hip/hip_runtime.h>

#define HW 9216
#define W 96
#define H 96
#define NC 256
#define NT 49
#define NPAIR 25
#define EPSV 1e-5f

#define TSX 16
#define TSY 8
#define NTHR 128
#define HROWS 14        // 8 + 6
#define HCOLS 22        // 16 + 6
#define CC 4
#define NZ 64           // 256 / 4

#define OUTS 384
#define SRCP 10

typedef _Float16 half4 __attribute__((ext_vector_type(4)));
typedef _Float16 half2v __attribute__((ext_vector_type(2)));

// ---- normw: normalize weights once, store packed fp16 pairs ----------------
__global__ __launch_bounds__(256) void normw_kernel(const float* __restrict__ w,
                                                    half2v* __restrict__ nwh) {
    const int p = blockIdx.x * 256 + threadIdx.x;
    float s = 0.f;
#pragma unroll
    for (int t = 0; t < NT; ++t) s += w[t * HW + p];
    const float inv = 1.f / (s + EPSV);
#pragma unroll
    for (int i = 0; i < NPAIR; ++i) {
        const float a = w[(2 * i) * HW + p] * inv;
        const float b = (2 * i + 1 < NT) ? w[(2 * i + 1) * HW + p] * inv : 0.f;
        half2v h;
        h[0] = (_Float16)a;
        h[1] = (_Float16)b;
        nwh[i * HW + p] = h;
    }
}

// ---- step1: CC=4 message passing, fp32 input -> fp16 output ----------------
__global__ __launch_bounds__(NTHR, 8) void step1_kernel(const float* __restrict__ x,
                                                        const half2v* __restrict__ nwh,
                                                        _Float16* __restrict__ x1h) {
    __shared__ half4 xs[HROWS][HCOLS];  // 2464 B
    const int tx = threadIdx.x & 15;
    const int ty = threadIdx.x >> 4;    // 0..7
    const int bx = blockIdx.x * TSX;
    const int by = blockIdx.y * TSY;
    const int px = bx + tx;
    const int py = by + ty;
    const int p = py * W + px;
    const int z = blockIdx.z;           // 0..63

    // stage 4 channels' 14x22 halo, packed fp16 (zero-padded)
    const float* __restrict__ xb = x + (size_t)z * CC * HW;
#pragma unroll
    for (int it = 0; it < 3; ++it) {
        const int i = threadIdx.x + it * NTHR;
        if (i < HROWS * HCOLS) {
            const int hy = i / HCOLS;
            const int hx = i - hy * HCOLS;
            const int gy = by - 3 + hy;
            const int gx = bx - 3 + hx;
            half4 h;
#pragma unroll
            for (int c = 0; c < CC; ++c) h[c] = (_Float16)0.f;
            if ((unsigned)gy < (unsigned)H && (unsigned)gx < (unsigned)W) {
                const float* sp = xb + gy * W + gx;
#pragma unroll
                for (int c = 0; c < CC; ++c) h[c] = (_Float16)sp[c * HW];
            }
            xs[hy][hx] = h;
        }
    }

    // prepacked weights: 25 dwords
    half2v wu[NPAIR];
#pragma unroll
    for (int i = 0; i < NPAIR; ++i) wu[i] = nwh[i * HW + p];
    __syncthreads();

    float acc[CC];
#pragma unroll
    for (int k = 0; k < CC; ++k) acc[k] = 0.f;
#pragma unroll
    for (int i = 0; i < 7; ++i) {
#pragma unroll
        for (int j = 0; j < 7; ++j) {
            const int t = i * 7 + j;
            const float wf = (float)wu[t >> 1][t & 1];
            const half4 v = xs[ty + i][tx + j];
#pragma unroll
            for (int k = 0; k < CC; ++k)
                acc[k] = fmaf(wf, (float)v[k], acc[k]);
        }
    }

    half4 h;
#pragma unroll
    for (int k = 0; k < CC; ++k) h[k] = (_Float16)acc[k];
    *(half4*)(x1h + ((size_t)z * HW + p) * CC) = h;
}

// ---- step2: CC=4 message passing + partial 1x1 conv ------------------------
__global__ __launch_bounds__(NTHR, 8) void step2_kernel(const _Float16* __restrict__ xin,
                                                        const half2v* __restrict__ nwh,
                                                        const float* __restrict__ cw,
                                                        float* __restrict__ partial) {
    __shared__ half4 xs[HROWS][HCOLS];
    const int tx = threadIdx.x & 15;
    const int ty = threadIdx.x >> 4;
    const int bx = blockIdx.x * TSX;
    const int by = blockIdx.y * TSY;
    const int px = bx + tx;
    const int py = by + ty;
    const int p = py * W + px;
    const int z = blockIdx.z;

    const _Float16* __restrict__ xz = xin + (size_t)z * HW * CC;
#pragma unroll
    for (int it = 0; it < 3; ++it) {
        const int i = threadIdx.x + it * NTHR;
        if (i < HROWS * HCOLS) {
            const int hy = i / HCOLS;
            const int hx = i - hy * HCOLS;
            const int gy = by - 3 + hy;
            const int gx = bx - 3 + hx;
            half4 v;
#pragma unroll
            for (int c = 0; c < CC; ++c) v[c] = (_Float16)0.f;
            if ((unsigned)gy < (unsigned)H && (unsigned)gx < (unsigned)W)
                v = *(const half4*)(xz + (size_t)(gy * W + gx) * CC);
            xs[hy][hx] = v;
        }
    }

    half2v wu[NPAIR];
#pragma unroll
    for (int i = 0; i < NPAIR; ++i) wu[i] = nwh[i * HW + p];
    __syncthreads();

    float acc[CC];
#pragma unroll
    for (int k = 0; k < CC; ++k) acc[k] = 0.f;
#pragma unroll
    for (int i = 0; i < 7; ++i) {
#pragma unroll
        for (int j = 0; j < 7; ++j) {
            const int t = i * 7 + j;
            const float wf = (float)wu[t >> 1][t & 1];
            const half4 v = xs[ty + i][tx + j];
#pragma unroll
            for (int k = 0; k < CC; ++k)
                acc[k] = fmaf(wf, (float)v[k], acc[k]);
        }
    }

    const int cbase = z * CC;
    float o0 = 0.f, o1 = 0.f, o2 = 0.f;
#pragma unroll
    for (int k = 0; k < CC; ++k) {
        const int c = cbase + k;
        o0 = fmaf(acc[k], cw[c], o0);
        o1 = fmaf(acc[k], cw[NC + c], o1);
        o2 = fmaf(acc[k], cw[2 * NC + c], o2);
    }
    partial[(z * 3 + 0) * HW + p] = o0;
    partial[(z * 3 + 1) * HW + p] = o1;
    partial[(z * 3 + 2) * HW + p] = o2;
}

// ---- fused z-reduce + bias + bilinear x4 upsample --------------------------
__global__ __launch_bounds__(256) void upsample_kernel(const float* __restrict__ partial,
                                                       const float* __restrict__ cb,
                                                       float* __restrict__ dst) {
    __shared__ float cvs[3][SRCP][SRCP];
    const int X = blockIdx.x * 32;
    const int Y = blockIdx.y * 32;
    const int x0s = X >> 2;
    const int y0s = Y >> 2;

    for (int e = threadIdx.x; e < 3 * SRCP * SRCP; e += 256) {
        int ch = e / (SRCP * SRCP);
        int r = e - ch * (SRCP * SRCP);
        int sy = r / SRCP;
        int sx = r - sy * SRCP;
        int gy = min(max(y0s - 1 + sy, 0), H - 1);
        int gx = min(max(x0s - 1 + sx, 0), W - 1);
        const int pp = gy * W + gx;
        float sum = cb[ch];
#pragma unroll 8
        for (int z = 0; z < NZ; ++z) sum += partial[(z * 3 + ch) * HW + pp];
        cvs[ch][sy][sx] = sum;
    }
    __syncthreads();

    const int xl = threadIdx.x & 31;
    const int yl0 = threadIdx.x >> 5;
    const int xo = X + xl;
    const float sxf = xo * 0.25f - 0.375f;
    const float fxf = floorf(sxf);
    const int jx = (int)fxf - (x0s - 1);
    const float fx = sxf - fxf;

#pragma unroll
    for (int k = 0; k < 4; ++k) {
        const int yo = Y + yl0 + 8 * k;
        const float syf = yo * 0.25f - 0.375f;
        const float fyf = floorf(syf);
        const int jy = (int)fyf - (y0s - 1);
        const float fy = syf - fyf;
#pragma unroll
        for (int ch = 0; ch < 3; ++ch) {
            const float v00 = cvs[ch][jy][jx], v01 = cvs[ch][jy][jx + 1];
            const float v10 = cvs[ch][jy + 1][jx], v11 = cvs[ch][jy + 1][jx + 1];
            const float v0 = v00 + (v01 - v00) * fx;
            const float v1 = v10 + (v11 - v10) * fx;
            dst[ch * OUTS * OUTS + yo * OUTS + xo] = v0 + (v1 - v0) * fy;
        }
    }
}

extern "C" void kernel_launch(void* const* d_in, const int* in_sizes, int n_in,
                              void* d_out, int out_size, void* d_ws, size_t ws_size,
                              hipStream_t stream) {
    const float* input  = (const float*)d_in[0];   // (1,256,96,96)
    const float* weight = (const float*)d_in[1];   // (1,49,9216)
    const float* conv_w = (const float*)d_in[2];   // (3,256)
    const float* conv_b = (const float*)d_in[3];   // (3,)
    float* out = (float*)d_out;                    // (1,3,384,384)

    char* ws = (char*)d_ws;
    half2v*   nwh   = (half2v*)ws;                              // 25*9216*4   = 0.92 MB
    _Float16* x1h   = (_Float16*)(ws + (size_t)NPAIR * HW * 4); // 256*9216*2  = 4.72 MB
    float*  partial = (float*)((char*)x1h + (size_t)NC * HW * 2); // 64*3*9216*4 = 7.08 MB

    normw_kernel<<<HW / 256, 256, 0, stream>>>(weight, nwh);

    dim3 g(W / TSX, H / TSY, NZ);             // (6,12,64) = 4608 blocks
    step1_kernel<<<g, NTHR, 0, stream>>>(input, nwh, x1h);
    step2_kernel<<<g, NTHR, 0, stream>>>(x1h, nwh, conv_w, partial);

    dim3 gu(OUTS / 32, OUTS / 32);            // (12,12)
    upsample_kernel<<<gu, 256, 0, stream>>>(partial, conv_b, out);
}

// Round 14
// 38.089 us; speedup vs baseline: 1.3147x; 1.1751x over previous
//
#include <hip/hip_runtime.h>

#define HW 9216
#define W 96
#define H 96
#define NC 256
#define NT 49
#define NPAIR 25
#define EPSV 1e-5f

#define TS 16
#define HSZ 22
#define CC 8
#define NZ 32

#define OUTS 384
#define SRCP 10

typedef _Float16 half8 __attribute__((ext_vector_type(8)));
typedef _Float16 half2v __attribute__((ext_vector_type(2)));

// ---- normw: normalize weights once, store packed fp16 pairs ----------------
// 72 blocks x 128 threads; coalesced loads (consecutive px within wave).
__global__ __launch_bounds__(128) void normw_kernel(const float* __restrict__ w,
                                                    half2v* __restrict__ nwh) {
    const int p = blockIdx.x * 128 + threadIdx.x;
    float s = 0.f;
#pragma unroll
    for (int t = 0; t < NT; ++t) s += w[t * HW + p];
    const float inv = 1.f / (s + EPSV);
#pragma unroll
    for (int i = 0; i < NPAIR; ++i) {
        const float a = w[(2 * i) * HW + p] * inv;
        const float b = (2 * i + 1 < NT) ? w[(2 * i + 1) * HW + p] * inv : 0.f;
        half2v h;
        h[0] = (_Float16)a;
        h[1] = (_Float16)b;
        nwh[i * HW + p] = h;
    }
}

// ---- step1: lean (prepacked weights) + direct fp32 staging -----------------
__global__ __launch_bounds__(256) void step1_kernel(const float* __restrict__ x,
                                                    const half2v* __restrict__ nwh,
                                                    _Float16* __restrict__ x1h) {
    __shared__ half8 xs[HSZ][HSZ];  // 7744 B
    const int tx = threadIdx.x & 15;
    const int ty = threadIdx.x >> 4;
    const int bx = blockIdx.x * TS;
    const int by = blockIdx.y * TS;
    const int px = bx + tx;
    const int py = by + ty;
    const int p = py * W + px;
    const int z = blockIdx.z;

    // stage 8 channels' 22x22 halo, packed fp16 (zero-padded)
    const float* __restrict__ xb = x + (size_t)z * CC * HW;
#pragma unroll
    for (int it = 0; it < 2; ++it) {
        const int i = threadIdx.x + it * 256;
        if (i < HSZ * HSZ) {
            const int hy = i / HSZ;
            const int hx = i - hy * HSZ;
            const int gy = by - 3 + hy;
            const int gx = bx - 3 + hx;
            half8 h;
#pragma unroll
            for (int c = 0; c < 8; ++c) h[c] = (_Float16)0.f;
            if ((unsigned)gy < (unsigned)H && (unsigned)gx < (unsigned)W) {
                const float* sp = xb + gy * W + gx;
#pragma unroll
                for (int c = 0; c < 8; ++c) h[c] = (_Float16)sp[c * HW];
            }
            xs[hy][hx] = h;
        }
    }

    // prepacked weights: 25 dwords
    half2v wu[NPAIR];
#pragma unroll
    for (int i = 0; i < NPAIR; ++i) wu[i] = nwh[i * HW + p];
    __syncthreads();

    float acc[8];
#pragma unroll
    for (int k = 0; k < 8; ++k) acc[k] = 0.f;
#pragma unroll
    for (int i = 0; i < 7; ++i) {
#pragma unroll
        for (int j = 0; j < 7; ++j) {
            const int t = i * 7 + j;
            const float wf = (float)wu[t >> 1][t & 1];
            const half8 v = xs[ty + i][tx + j];
#pragma unroll
            for (int k = 0; k < 8; ++k)
                acc[k] = fmaf(wf, (float)v[k], acc[k]);
        }
    }

    half8 h;
#pragma unroll
    for (int k = 0; k < 8; ++k) h[k] = (_Float16)acc[k];
    *(half8*)(x1h + ((size_t)z * HW + p) * 8) = h;
}

// ---- step2: lean + partial 1x1 conv ----------------------------------------
__global__ __launch_bounds__(256) void step2_kernel(const _Float16* __restrict__ xin,
                                                    const half2v* __restrict__ nwh,
                                                    const float* __restrict__ cw,
                                                    float* __restrict__ partial) {
    __shared__ half8 xs[HSZ][HSZ];
    const int tx = threadIdx.x & 15;
    const int ty = threadIdx.x >> 4;
    const int bx = blockIdx.x * TS;
    const int by = blockIdx.y * TS;
    const int px = bx + tx;
    const int py = by + ty;
    const int p = py * W + px;
    const int z = blockIdx.z;

    const _Float16* __restrict__ xz = xin + (size_t)z * HW * 8;
#pragma unroll
    for (int it = 0; it < 2; ++it) {
        const int i = threadIdx.x + it * 256;
        if (i < HSZ * HSZ) {
            const int hy = i / HSZ;
            const int hx = i - hy * HSZ;
            const int gy = by - 3 + hy;
            const int gx = bx - 3 + hx;
            half8 v;
#pragma unroll
            for (int c = 0; c < 8; ++c) v[c] = (_Float16)0.f;
            if ((unsigned)gy < (unsigned)H && (unsigned)gx < (unsigned)W)
                v = *(const half8*)(xz + (size_t)(gy * W + gx) * 8);
            xs[hy][hx] = v;
        }
    }

    half2v wu[NPAIR];
#pragma unroll
    for (int i = 0; i < NPAIR; ++i) wu[i] = nwh[i * HW + p];
    __syncthreads();

    float acc[8];
#pragma unroll
    for (int k = 0; k < 8; ++k) acc[k] = 0.f;
#pragma unroll
    for (int i = 0; i < 7; ++i) {
#pragma unroll
        for (int j = 0; j < 7; ++j) {
            const int t = i * 7 + j;
            const float wf = (float)wu[t >> 1][t & 1];
            const half8 v = xs[ty + i][tx + j];
#pragma unroll
            for (int k = 0; k < 8; ++k)
                acc[k] = fmaf(wf, (float)v[k], acc[k]);
        }
    }

    float o0 = 0.f, o1 = 0.f, o2 = 0.f;
    const int cbase = z * CC;
#pragma unroll
    for (int k = 0; k < 8; ++k) {
        const int c = cbase + k;
        o0 = fmaf(acc[k], cw[c], o0);
        o1 = fmaf(acc[k], cw[NC + c], o1);
        o2 = fmaf(acc[k], cw[2 * NC + c], o2);
    }
    partial[(z * 3 + 0) * HW + p] = o0;
    partial[(z * 3 + 1) * HW + p] = o1;
    partial[(z * 3 + 2) * HW + p] = o2;
}

// ---- fused z-reduce + bias + bilinear x4 upsample --------------------------
__global__ __launch_bounds__(256) void upsample_kernel(const float* __restrict__ partial,
                                                       const float* __restrict__ cb,
                                                       float* __restrict__ dst) {
    __shared__ float cvs[3][SRCP][SRCP];
    const int X = blockIdx.x * 32;
    const int Y = blockIdx.y * 32;
    const int x0s = X >> 2;
    const int y0s = Y >> 2;

    for (int e = threadIdx.x; e < 3 * SRCP * SRCP; e += 256) {
        int ch = e / (SRCP * SRCP);
        int r = e - ch * (SRCP * SRCP);
        int sy = r / SRCP;
        int sx = r - sy * SRCP;
        int gy = min(max(y0s - 1 + sy, 0), H - 1);
        int gx = min(max(x0s - 1 + sx, 0), W - 1);
        const int pp = gy * W + gx;
        float sum = cb[ch];
#pragma unroll
        for (int z = 0; z < NZ; ++z) sum += partial[(z * 3 + ch) * HW + pp];
        cvs[ch][sy][sx] = sum;
    }
    __syncthreads();

    const int xl = threadIdx.x & 31;
    const int yl0 = threadIdx.x >> 5;
    const int xo = X + xl;
    const float sxf = xo * 0.25f - 0.375f;
    const float fxf = floorf(sxf);
    const int jx = (int)fxf - (x0s - 1);
    const float fx = sxf - fxf;

#pragma unroll
    for (int k = 0; k < 4; ++k) {
        const int yo = Y + yl0 + 8 * k;
        const float syf = yo * 0.25f - 0.375f;
        const float fyf = floorf(syf);
        const int jy = (int)fyf - (y0s - 1);
        const float fy = syf - fyf;
#pragma unroll
        for (int ch = 0; ch < 3; ++ch) {
            const float v00 = cvs[ch][jy][jx], v01 = cvs[ch][jy][jx + 1];
            const float v10 = cvs[ch][jy + 1][jx], v11 = cvs[ch][jy + 1][jx + 1];
            const float v0 = v00 + (v01 - v00) * fx;
            const float v1 = v10 + (v11 - v10) * fx;
            dst[ch * OUTS * OUTS + yo * OUTS + xo] = v0 + (v1 - v0) * fy;
        }
    }
}

extern "C" void kernel_launch(void* const* d_in, const int* in_sizes, int n_in,
                              void* d_out, int out_size, void* d_ws, size_t ws_size,
                              hipStream_t stream) {
    const float* input  = (const float*)d_in[0];   // (1,256,96,96)
    const float* weight = (const float*)d_in[1];   // (1,49,9216)
    const float* conv_w = (const float*)d_in[2];   // (3,256)
    const float* conv_b = (const float*)d_in[3];   // (3,)
    float* out = (float*)d_out;                    // (1,3,384,384)

    char* ws = (char*)d_ws;
    half2v*   nwh   = (half2v*)ws;                              // 0.92 MB
    _Float16* x1h   = (_Float16*)(ws + (size_t)NPAIR * HW * 4); // 4.72 MB
    float*  partial = (float*)((char*)x1h + (size_t)NC * HW * 2);

    normw_kernel<<<HW / 128, 128, 0, stream>>>(weight, nwh);

    dim3 g(W / TS, H / TS, NZ);               // (6,6,32)
    step1_kernel<<<g, 256, 0, stream>>>(input, nwh, x1h);
    step2_kernel<<<g, 256, 0, stream>>>(x1h, nwh, conv_w, partial);

    dim3 gu(OUTS / 32, OUTS / 32);            // (12,12)
    upsample_kernel<<<gu, 256, 0, stream>>>(partial, conv_b, out);
}

// Round 15
// 34.778 us; speedup vs baseline: 1.4399x; 1.0952x over previous
//
#include <hip/hip_runtime.h>

#define HW 9216
#define W 96
#define H 96
#define NC 256
#define NT 49
#define NPAIR 25
#define EPSV 1e-5f

#define TS 16
#define HSZ 22
#define CC 8
#define NZ 32

#define OUTS 384
#define SRCP 10

typedef _Float16 half8 __attribute__((ext_vector_type(8)));
typedef _Float16 half2v __attribute__((ext_vector_type(2)));

// ---- step1: fused pack + normalize + message passing -----------------------
// Reads fp32 x (c-major strided), normalizes weights in fp32 regs, writes
// packed-fp16 x1h[z][p][8]; z==0 blocks also emit packed nwh for step2.
__global__ __launch_bounds__(256) void step1_kernel(const float* __restrict__ x,
                                                    const float* __restrict__ w,
                                                    _Float16* __restrict__ x1h,
                                                    half2v* __restrict__ nwh) {
    __shared__ half8 xs[HSZ][HSZ];  // 7744 B
    const int tx = threadIdx.x & 15;
    const int ty = threadIdx.x >> 4;
    const int bx = blockIdx.x * TS;
    const int by = blockIdx.y * TS;
    const int px = bx + tx;
    const int py = by + ty;
    const int p = py * W + px;
    const int z = blockIdx.z;

    // ---- issue halo loads FIRST (latency hides under weight normalize) ----
    const float* __restrict__ xb = x + (size_t)z * CC * HW;
    float hv[2][8];
    int hidx[2];
#pragma unroll
    for (int it = 0; it < 2; ++it) {
        const int i = threadIdx.x + it * 256;
        hidx[it] = i;
#pragma unroll
        for (int c = 0; c < 8; ++c) hv[it][c] = 0.f;
        if (i < HSZ * HSZ) {
            const int hy = i / HSZ;
            const int hx = i - hy * HSZ;
            const int gy = by - 3 + hy;
            const int gx = bx - 3 + hx;
            if ((unsigned)gy < (unsigned)H && (unsigned)gx < (unsigned)W) {
                const float* sp = xb + gy * W + gx;
#pragma unroll
                for (int c = 0; c < 8; ++c) hv[it][c] = sp[c * HW];
            }
        }
    }

    // ---- load + normalize the 49 per-pixel weights (fp32 regs) ----
    float wreg[NT];
    float s = 0.f;
#pragma unroll
    for (int t = 0; t < NT; ++t) { wreg[t] = w[t * HW + p]; s += wreg[t]; }
    const float inv = 1.f / (s + EPSV);
#pragma unroll
    for (int t = 0; t < NT; ++t) wreg[t] *= inv;

    // z==0 blocks publish packed fp16 weights for step2
    if (z == 0) {
#pragma unroll
        for (int i = 0; i < NPAIR; ++i) {
            half2v h;
            h[0] = (_Float16)wreg[2 * i];
            h[1] = (2 * i + 1 < NT) ? (_Float16)wreg[2 * i + 1] : (_Float16)0.f;
            nwh[i * HW + p] = h;
        }
    }

    // ---- convert + stage halo to LDS ----
#pragma unroll
    for (int it = 0; it < 2; ++it) {
        const int i = hidx[it];
        if (i < HSZ * HSZ) {
            const int hy = i / HSZ;
            const int hx = i - hy * HSZ;
            half8 h;
#pragma unroll
            for (int c = 0; c < 8; ++c) h[c] = (_Float16)hv[it][c];
            xs[hy][hx] = h;
        }
    }
    __syncthreads();

    float acc[8];
#pragma unroll
    for (int k = 0; k < 8; ++k) acc[k] = 0.f;

#pragma unroll
    for (int i = 0; i < 7; ++i) {
#pragma unroll
        for (int j = 0; j < 7; ++j) {
            const float wf = wreg[i * 7 + j];
            const half8 v = xs[ty + i][tx + j];
#pragma unroll
            for (int k = 0; k < 8; ++k)
                acc[k] = fmaf(wf, (float)v[k], acc[k]);
        }
    }

    half8 h;
#pragma unroll
    for (int k = 0; k < 8; ++k) h[k] = (_Float16)acc[k];
    *(half8*)(x1h + ((size_t)z * HW + p) * 8) = h;
}

// ---- step2: lean (packed weights + packed staging) + partial 1x1 conv ------
__global__ __launch_bounds__(256) void step2_kernel(const _Float16* __restrict__ xin,
                                                    const half2v* __restrict__ nwh,
                                                    const float* __restrict__ cw,
                                                    float* __restrict__ partial) {
    __shared__ half8 xs[HSZ][HSZ];
    const int tx = threadIdx.x & 15;
    const int ty = threadIdx.x >> 4;
    const int bx = blockIdx.x * TS;
    const int by = blockIdx.y * TS;
    const int px = bx + tx;
    const int py = by + ty;
    const int p = py * W + px;
    const int z = blockIdx.z;

    // stage halo (issue loads first)
    const _Float16* __restrict__ xz = xin + (size_t)z * HW * 8;
    half8 hv[2];
    int hidx[2];
#pragma unroll
    for (int it = 0; it < 2; ++it) {
        const int i = threadIdx.x + it * 256;
        hidx[it] = i;
#pragma unroll
        for (int c = 0; c < 8; ++c) hv[it][c] = (_Float16)0.f;
        if (i < HSZ * HSZ) {
            const int hy = i / HSZ;
            const int hx = i - hy * HSZ;
            const int gy = by - 3 + hy;
            const int gx = bx - 3 + hx;
            if ((unsigned)gy < (unsigned)H && (unsigned)gx < (unsigned)W)
                hv[it] = *(const half8*)(xz + (size_t)(gy * W + gx) * 8);
        }
    }

    // 25 packed weight dwords (normalized fp16 pairs)
    half2v wu[NPAIR];
#pragma unroll
    for (int i = 0; i < NPAIR; ++i) wu[i] = nwh[i * HW + p];

#pragma unroll
    for (int it = 0; it < 2; ++it) {
        const int i = hidx[it];
        if (i < HSZ * HSZ) {
            const int hy = i / HSZ;
            const int hx = i - hy * HSZ;
            xs[hy][hx] = hv[it];
        }
    }
    __syncthreads();

    float acc[8];
#pragma unroll
    for (int k = 0; k < 8; ++k) acc[k] = 0.f;

#pragma unroll
    for (int i = 0; i < 7; ++i) {
#pragma unroll
        for (int j = 0; j < 7; ++j) {
            const int t = i * 7 + j;
            const float wf = (float)wu[t >> 1][t & 1];
            const half8 v = xs[ty + i][tx + j];
#pragma unroll
            for (int k = 0; k < 8; ++k)
                acc[k] = fmaf(wf, (float)v[k], acc[k]);
        }
    }

    float o0 = 0.f, o1 = 0.f, o2 = 0.f;
    const int cbase = z * CC;
#pragma unroll
    for (int k = 0; k < 8; ++k) {
        const int c = cbase + k;
        o0 = fmaf(acc[k], cw[c], o0);
        o1 = fmaf(acc[k], cw[NC + c], o1);
        o2 = fmaf(acc[k], cw[2 * NC + c], o2);
    }
    partial[(z * 3 + 0) * HW + p] = o0;
    partial[(z * 3 + 1) * HW + p] = o1;
    partial[(z * 3 + 2) * HW + p] = o2;
}

// ---- fused z-reduce + bias + bilinear x4 upsample --------------------------
__global__ __launch_bounds__(256) void upsample_kernel(const float* __restrict__ partial,
                                                       const float* __restrict__ cb,
                                                       float* __restrict__ dst) {
    __shared__ float cvs[3][SRCP][SRCP];
    const int X = blockIdx.x * 32;
    const int Y = blockIdx.y * 32;
    const int x0s = X >> 2;
    const int y0s = Y >> 2;

    for (int e = threadIdx.x; e < 3 * SRCP * SRCP; e += 256) {
        int ch = e / (SRCP * SRCP);
        int r = e - ch * (SRCP * SRCP);
        int sy = r / SRCP;
        int sx = r - sy * SRCP;
        int gy = min(max(y0s - 1 + sy, 0), H - 1);
        int gx = min(max(x0s - 1 + sx, 0), W - 1);
        const int pp = gy * W + gx;
        float sum = cb[ch];
#pragma unroll
        for (int z = 0; z < NZ; ++z) sum += partial[(z * 3 + ch) * HW + pp];
        cvs[ch][sy][sx] = sum;
    }
    __syncthreads();

    const int xl = threadIdx.x & 31;
    const int yl0 = threadIdx.x >> 5;
    const int xo = X + xl;
    const float sxf = xo * 0.25f - 0.375f;
    const float fxf = floorf(sxf);
    const int jx = (int)fxf - (x0s - 1);
    const float fx = sxf - fxf;

#pragma unroll
    for (int k = 0; k < 4; ++k) {
        const int yo = Y + yl0 + 8 * k;
        const float syf = yo * 0.25f - 0.375f;
        const float fyf = floorf(syf);
        const int jy = (int)fyf - (y0s - 1);
        const float fy = syf - fyf;
#pragma unroll
        for (int ch = 0; ch < 3; ++ch) {
            const float v00 = cvs[ch][jy][jx], v01 = cvs[ch][jy][jx + 1];
            const float v10 = cvs[ch][jy + 1][jx], v11 = cvs[ch][jy + 1][jx + 1];
            const float v0 = v00 + (v01 - v00) * fx;
            const float v1 = v10 + (v11 - v10) * fx;
            dst[ch * OUTS * OUTS + yo * OUTS + xo] = v0 + (v1 - v0) * fy;
        }
    }
}

extern "C" void kernel_launch(void* const* d_in, const int* in_sizes, int n_in,
                              void* d_out, int out_size, void* d_ws, size_t ws_size,
                              hipStream_t stream) {
    const float* input  = (const float*)d_in[0];   // (1,256,96,96)
    const float* weight = (const float*)d_in[1];   // (1,49,9216)
    const float* conv_w = (const float*)d_in[2];   // (3,256)
    const float* conv_b = (const float*)d_in[3];   // (3,)
    float* out = (float*)d_out;                    // (1,3,384,384)

    char* ws = (char*)d_ws;
    _Float16* x1h   = (_Float16*)ws;                         // 4.72 MB
    half2v*   nwh   = (half2v*)(x1h + (size_t)NZ * HW * 8);  // 0.92 MB
    float*  partial = (float*)((char*)nwh + (size_t)NPAIR * HW * 4);

    dim3 g(W / TS, H / TS, NZ);               // (6,6,32)
    step1_kernel<<<g, 256, 0, stream>>>(input, weight, x1h, nwh);
    step2_kernel<<<g, 256, 0, stream>>>(x1h, nwh, conv_w, partial);

    dim3 gu(OUTS / 32, OUTS / 32);            // (12,12)
    upsample_kernel<<<gu, 256, 0, stream>>>(partial, conv_b, out);
}